// Round 1
// 615.644 us; speedup vs baseline: 1.2333x; 1.2333x over previous
//
#include <hip/hip_runtime.h>

// VQ nearest-codebook: N=262144 rows x D=64, K=1024 codes.
// Numerics contract (bit-exact vs np f32 reference, verified in prior session):
//   dist_k = fl32( fl32(zsq - 2*dot_k) + cbsq_k ), argmin -> lowest index wins.
//   dot_k MUST be one sequential fmaf chain d=0..63 per row. DO NOT re-associate.
//   zsq/cbsq: f64-accumulate then round once.
//
// R4 change: register-block TWO rows per thread (R=2).
//   Rationale (rocprof r3): VALUBusy 71.5%, HBM 4%, useful-FMA floor 218us vs
//   759us wall. Each c-row load fed only 64 FMAs and the 64-deep dependent
//   chain leaves a lone wave issue-idle half the time. Two independent chains
//   interleaved (s0/s1) saturate issue (4-cyc dep = 2 inst x 2 cyc) and halve
//   loads-per-FMA. q rows in 32 NAMED float4s (NO arrays -> no scratch).
//   __launch_bounds__(256,2): cap 256 VGPR for ~212 live; grid 512 = 2 blk/CU.

#define VQ_D 64
#define VQ_MAXK 1024

// Two-row sequential fused-FMA chain step over one float4 (ascending d within
// each row's chain; the two chains are independent -> ILP without reassociation).
#define VQ_CH2(qa, qb, c) do { \
    s0 = fmaf((qa).x, (c).x, s0); s1 = fmaf((qb).x, (c).x, s1); \
    s0 = fmaf((qa).y, (c).y, s0); s1 = fmaf((qb).y, (c).y, s1); \
    s0 = fmaf((qa).z, (c).z, s0); s1 = fmaf((qb).z, (c).z, s1); \
    s0 = fmaf((qa).w, (c).w, s0); s1 = fmaf((qb).w, (c).w, s1); } while (0)

// f64 sum-of-squares over one float4 (order-free: tie-invariant).
#define VQ_SQ(acc, q) do { \
    (acc) += (double)(q).x * (double)(q).x; \
    (acc) += (double)(q).y * (double)(q).y; \
    (acc) += (double)(q).z * (double)(q).z; \
    (acc) += (double)(q).w * (double)(q).w; } while (0)

__global__ __launch_bounds__(256, 2) void vq_argmin_kernel(
    const float* __restrict__ z_e,
    const float* __restrict__ cb,
    float* __restrict__ out,   // [N*D] z_q, then [N] indices (as float)
    int N, int K)
{
    __shared__ float s_cbsq[VQ_MAXK];

    // cb_sq per code: f64 accumulate, round once to f32. (Verified numerics —
    // do not change.)
    for (int k = threadIdx.x; k < K; k += blockDim.x) {
        const float* c = cb + (size_t)k * VQ_D;
        double s = 0.0;
        #pragma unroll
        for (int d = 0; d < VQ_D; ++d) { double v = (double)c[d]; s += v * v; }
        s_cbsq[k] = (float)s;
    }
    __syncthreads();

    // Two rows per thread: n0 = b*512 + t, n1 = n0 + 256.
    int n0 = blockIdx.x * (2 * blockDim.x) + threadIdx.x;
    if (n0 >= N) return;
    int n1 = n0 + blockDim.x;
    if (n1 >= N) n1 = n0;  // harmless duplicate; never hit at N=262144

    // Both z rows in 32 NAMED float4 registers (NOT arrays — scratch hazard).
    const float4* zp0 = (const float4*)(z_e + (size_t)n0 * VQ_D);
    const float4* zp1 = (const float4*)(z_e + (size_t)n1 * VQ_D);
    float4 a0  = zp0[0],  a1  = zp0[1],  a2  = zp0[2],  a3  = zp0[3];
    float4 a4  = zp0[4],  a5  = zp0[5],  a6  = zp0[6],  a7  = zp0[7];
    float4 a8  = zp0[8],  a9  = zp0[9],  a10 = zp0[10], a11 = zp0[11];
    float4 a12 = zp0[12], a13 = zp0[13], a14 = zp0[14], a15 = zp0[15];
    float4 b0  = zp1[0],  b1  = zp1[1],  b2  = zp1[2],  b3  = zp1[3];
    float4 b4  = zp1[4],  b5  = zp1[5],  b6  = zp1[6],  b7  = zp1[7];
    float4 b8  = zp1[8],  b9  = zp1[9],  b10 = zp1[10], b11 = zp1[11];
    float4 b12 = zp1[12], b13 = zp1[13], b14 = zp1[14], b15 = zp1[15];

    // ||z||^2 in f64, rounded once (per row).
    double zs0 = 0.0, zs1 = 0.0;
    VQ_SQ(zs0, a0);  VQ_SQ(zs0, a1);  VQ_SQ(zs0, a2);  VQ_SQ(zs0, a3);
    VQ_SQ(zs0, a4);  VQ_SQ(zs0, a5);  VQ_SQ(zs0, a6);  VQ_SQ(zs0, a7);
    VQ_SQ(zs0, a8);  VQ_SQ(zs0, a9);  VQ_SQ(zs0, a10); VQ_SQ(zs0, a11);
    VQ_SQ(zs0, a12); VQ_SQ(zs0, a13); VQ_SQ(zs0, a14); VQ_SQ(zs0, a15);
    VQ_SQ(zs1, b0);  VQ_SQ(zs1, b1);  VQ_SQ(zs1, b2);  VQ_SQ(zs1, b3);
    VQ_SQ(zs1, b4);  VQ_SQ(zs1, b5);  VQ_SQ(zs1, b6);  VQ_SQ(zs1, b7);
    VQ_SQ(zs1, b8);  VQ_SQ(zs1, b9);  VQ_SQ(zs1, b10); VQ_SQ(zs1, b11);
    VQ_SQ(zs1, b12); VQ_SQ(zs1, b13); VQ_SQ(zs1, b14); VQ_SQ(zs1, b15);
    const float zsq0 = (float)zs0;
    const float zsq1 = (float)zs1;

    float best0 = 3.4e38f, best1 = 3.4e38f;
    int bk0 = 0, bk1 = 0;

    #pragma unroll 1
    for (int k = 0; k < K; ++k) {
        // Wave-uniform row address; 16 up-front loads, progressive vmcnt waits
        // inside the chain, one stall at the top of the iteration.
        const float4* __restrict__ cp = (const float4*)(cb + (size_t)k * VQ_D);
        float4 c0  = cp[0],  c1  = cp[1],  c2  = cp[2],  c3  = cp[3];
        float4 c4  = cp[4],  c5  = cp[5],  c6  = cp[6],  c7  = cp[7];
        float4 c8  = cp[8],  c9  = cp[9],  c10 = cp[10], c11 = cp[11];
        float4 c12 = cp[12], c13 = cp[13], c14 = cp[14], c15 = cp[15];

        // Two sequential fused-FMA chains, ascending d, interleaved. DO NOT
        // reorder within a chain.
        float s0 = 0.f, s1 = 0.f;
        VQ_CH2(a0,  b0,  c0);  VQ_CH2(a1,  b1,  c1);
        VQ_CH2(a2,  b2,  c2);  VQ_CH2(a3,  b3,  c3);
        VQ_CH2(a4,  b4,  c4);  VQ_CH2(a5,  b5,  c5);
        VQ_CH2(a6,  b6,  c6);  VQ_CH2(a7,  b7,  c7);
        VQ_CH2(a8,  b8,  c8);  VQ_CH2(a9,  b9,  c9);
        VQ_CH2(a10, b10, c10); VQ_CH2(a11, b11, c11);
        VQ_CH2(a12, b12, c12); VQ_CH2(a13, b13, c13);
        VQ_CH2(a14, b14, c14); VQ_CH2(a15, b15, c15);

        const float cq = s_cbsq[k];
        const float u0    = zsq0 - 2.0f * s0;   // fp32 round, as reference
        const float dist0 = u0 + cq;            // fp32 round, as reference
        const float u1    = zsq1 - 2.0f * s1;
        const float dist1 = u1 + cq;
        if (dist0 < best0) { best0 = dist0; bk0 = k; }  // strict <: lowest k wins
        if (dist1 < best1) { best1 = dist1; bk1 = k; }
    }

    // z_q gathers (codebook L2/L3-resident), float4 stores.
    {
        const float4* cq0 = (const float4*)(cb + (size_t)bk0 * VQ_D);
        float4* oq0 = (float4*)(out + (size_t)n0 * VQ_D);
        #pragma unroll
        for (int i = 0; i < VQ_D / 4; ++i) oq0[i] = cq0[i];
        const float4* cq1 = (const float4*)(cb + (size_t)bk1 * VQ_D);
        float4* oq1 = (float4*)(out + (size_t)n1 * VQ_D);
        #pragma unroll
        for (int i = 0; i < VQ_D / 4; ++i) oq1[i] = cq1[i];
    }

    // Indices as float (exact for k < 2^24).
    out[(size_t)N * VQ_D + n0] = (float)bk0;
    out[(size_t)N * VQ_D + n1] = (float)bk1;
}

extern "C" void kernel_launch(void* const* d_in, const int* in_sizes, int n_in,
                              void* d_out, int out_size, void* d_ws, size_t ws_size,
                              hipStream_t stream) {
    const float* z_e = (const float*)d_in[0];
    const float* cb  = (const float*)d_in[1];
    float* out = (float*)d_out;

    const int N = in_sizes[0] / VQ_D;
    const int K = in_sizes[1] / VQ_D;

    const int block = 256;
    const int rows_per_block = 2 * block;
    const int grid = (N + rows_per_block - 1) / rows_per_block;
    vq_argmin_kernel<<<grid, block, 0, stream>>>(z_e, cb, out, N, K);
}